// Round 3
// baseline (1212.045 us; speedup 1.0000x reference)
//
#include <hip/hip_runtime.h>

// LowRankKVCache: out = X @ Vt^T @ Vt where Vt = top-64 eigenvectors of X^T X.
// 64 independent 2048x128 fp32 matrices (B*H = 4*16).
//
// Round 6 (resubmit; round-2 bench was an infra failure): hierarchical
// (wave-local) one-sided Jacobi. Each wave privately hosts 16 columns
// (2/octet in VGPRs). Inner exchanges are within-wave LDS with
// s_waitcnt lgkmcnt(0) only -- NO block barriers (waves pipeline
// independently, DS and VALU overlap). Outer: round-robin tournament on 16
// half-blocks of 8 cols (wave W hosts positions W, 15-W); per cycle:
//   1 local odd-even sweep (intra pairs, 8 A+B rounds, barrier-free)
//   15 x [cross-only meeting (8-round ring over co-half) + position rotate
//        (the only 3 __syncthreads per outer step)]
// Coverage/cycle: every column pair >= 1 rotation (8640 rotations ~= 1.06
// classic sweeps); NCYC=7 ~= the old 7-sweep budget. Barriers: 896 -> 315.
// LDS slots stride 33 float4 -> octet chunks start at staggered banks.
//
// ws layout (bytes):
//   [0, 4M)        G      (64 x 128x128 f32)   -- dead after jacobi
//   [4M, 8M)       Vfull  (64 x 128x128 f32)   -- dead after select_k
//   [8M, 8M+32K)   normg  (64 x 128 f32)       -- dead after select_k
//   [32M, 34M)     Vt     (64 x 64x128 f32)
//   [0, 32M)       W      (64 x 2048x64 f32)   -- overlays dead G/Vfull/normg
// total requirement: 34 MB of d_ws.

#define NM 64
#define SEQ 2048
#define DD 128
#define RR 64
#define NCYC 7

#define OFF_VFULL (4194304ULL)
#define OFF_NORM  (8388608ULL)
#define OFF_VT    (33554432ULL)

__device__ __forceinline__ float dot4(float4 a, float4 b) {
  return a.x * b.x + a.y * b.y + a.z * b.z + a.w * b.w;
}

// DPP butterfly add over aligned 8-lane groups (VALU pipe).
template <int CTRL>
__device__ __forceinline__ float dpp_add(float x) {
  int y = __builtin_amdgcn_update_dpp(0, __float_as_int(x), CTRL, 0xf, 0xf, true);
  return x + __int_as_float(y);
}
__device__ __forceinline__ float red8(float x) {  // sum over aligned 8 lanes
  x = dpp_add<0xB1>(x);   // quad xor1
  x = dpp_add<0x4E>(x);   // quad xor2
  x = dpp_add<0x141>(x);  // row_half_mirror
  return x;
}

// Within-wave LDS fence: same-wave DS ops are processed in order; lgkmcnt(0)
// guarantees prior ds_writes are complete before subsequent ds_reads issue.
// sched_barrier(0) stops the compiler hoisting ops past the asm (rule #18).
__device__ __forceinline__ void waitlds() {
  asm volatile("s_waitcnt lgkmcnt(0)" ::: "memory");
  __builtin_amdgcn_sched_barrier(0);
}

// Jacobi rotation angle from the pair's 2x2 Gram. false => identity.
__device__ __forceinline__ bool jrot(float app, float apq, float aqq,
                                     float& c, float& s) {
  if (apq * apq <= 1e-9f * app * aqq) return false;
  float tau = (aqq - app) / (2.f * apq);
  float tv = 1.f / (fabsf(tau) + sqrtf(1.f + tau * tau));
  tv = tau < 0.f ? -tv : tv;
  c = 1.f / sqrtf(1.f + tv * tv);
  s = tv * c;
  return true;
}

__device__ __forceinline__ void rot4(float c, float s, float4 p, float4 q,
                                     float4& np, float4& nq) {
  np.x = c * p.x - s * q.x;  nq.x = s * p.x + c * q.x;
  np.y = c * p.y - s * q.y;  nq.y = s * p.y + c * q.y;
  np.z = c * p.z - s * q.z;  nq.z = s * p.z + c * q.z;
  np.w = c * p.w - s * q.w;  nq.w = s * p.w + c * q.w;
}

// ---------------- K1: Gram G[m] = X[m]^T X[m] ----------------
__global__ __launch_bounds__(256) void gram_k(const float* __restrict__ X,
                                              float* __restrict__ G) {
  const int m = blockIdx.y;
  const int r0 = blockIdx.x * 32;  // G row tile (== X column tile)
  const int tid = threadIdx.x;
  __shared__ __align__(16) float Xs[64][128];  // 32 KB
  const float* Xm = X + (size_t)m * SEQ * DD;
  const int ti = tid >> 5;  // 0..7  -> G rows r0+4ti..+3
  const int tj = tid & 31;  // 0..31 -> G cols 4tj..+3
  float acc[4][4];
#pragma unroll
  for (int a = 0; a < 4; ++a)
#pragma unroll
    for (int b = 0; b < 4; ++b) acc[a][b] = 0.f;

  for (int s0 = 0; s0 < SEQ; s0 += 64) {
    __syncthreads();
    for (int t = tid; t < 2048; t += 256) {  // 64 rows x 32 float4
      int s = t >> 5, c4 = t & 31;
      *(float4*)&Xs[s][c4 * 4] =
          *(const float4*)&Xm[(size_t)(s0 + s) * DD + c4 * 4];
    }
    __syncthreads();
#pragma unroll 4
    for (int s = 0; s < 64; ++s) {
      float4 av = *(const float4*)&Xs[s][r0 + 4 * ti];
      float4 bv = *(const float4*)&Xs[s][4 * tj];
      acc[0][0] += av.x * bv.x; acc[0][1] += av.x * bv.y;
      acc[0][2] += av.x * bv.z; acc[0][3] += av.x * bv.w;
      acc[1][0] += av.y * bv.x; acc[1][1] += av.y * bv.y;
      acc[1][2] += av.y * bv.z; acc[1][3] += av.y * bv.w;
      acc[2][0] += av.z * bv.x; acc[2][1] += av.z * bv.y;
      acc[2][2] += av.z * bv.z; acc[2][3] += av.z * bv.w;
      acc[3][0] += av.w * bv.x; acc[3][1] += av.w * bv.y;
      acc[3][2] += av.w * bv.z; acc[3][3] += av.w * bv.w;
    }
  }
  float* Gm = G + (size_t)m * DD * DD;
#pragma unroll
  for (int a = 0; a < 4; ++a) {
    float4 v = make_float4(acc[a][0], acc[a][1], acc[a][2], acc[a][3]);
    *(float4*)&Gm[(size_t)(r0 + 4 * ti + a) * DD + 4 * tj] = v;
  }
}

// ---------------- K2: hierarchical Jacobi (see header comment) -------------
// 512 threads = 8 waves x 8 octets x 8 lanes. Octet o of wave W holds two
// columns in registers: ce (position-W half, col o) and co (position-(15-W)
// half, col o); lane l holds float4s {l, l+8, l+16, l+24} of each column.
__global__ __launch_bounds__(512) void jacobi_hier_k(const float* __restrict__ G,
                                                     float* __restrict__ Vfull,
                                                     float* __restrict__ normg) {
  const int m = blockIdx.x;
  const int tid = threadIdx.x;
  const int W = tid >> 6;        // wave 0..7
  const int o = (tid >> 3) & 7;  // octet in wave
  const int l = tid & 7;         // lane in octet
  __shared__ float4 buf[4096];   // 64 KB, overlaid:
  // meeting/local slots: wave W slot s at buf[W*264 + s*33] (bank-staggered)
  // outer position slots: position p col c at buf[p*256 + c*32]
  float4* M = &buf[W * 264];

  // G is symmetric: column j of G == row j of G -> transpose-free load.
  const float4* Gm4 = (const float4*)(G + (size_t)m * DD * DD);
  float4 ce[4], co[4];
#pragma unroll
  for (int j = 0; j < 4; ++j) {
    ce[j] = Gm4[(size_t)(8 * W + o) * 32 + l + 8 * j];
    co[j] = Gm4[(size_t)(8 * (15 - W) + o) * 32 + l + 8 * j];
  }
  // Tournament routing: pos 0 fixed; p -> p+1 (p=1..14); 15 -> 1.
  const int dst_ce = (W == 0) ? 0 : W + 1;   // new home of my ce half-block
  const int dst_co = (W == 0) ? 1 : 16 - W;  // new home of my co half-block

#pragma unroll 1
  for (int cyc = 0; cyc < NCYC; ++cyc) {
    // ---- local odd-even sweep over the wave's 16 resident columns --------
    // (covers intra-half pairs; barrier-free; always-swap; ends reversed)
#pragma unroll 1
    for (int r = 0; r < 8; ++r) {
      {  // A-step: slots (2o, 2o+1) = (ce, co), register-only
        float app = 0.f, apq = 0.f, aqq = 0.f;
#pragma unroll
        for (int j = 0; j < 4; ++j) {
          app += dot4(ce[j], ce[j]);
          apq += dot4(ce[j], co[j]);
          aqq += dot4(co[j], co[j]);
        }
        app = red8(app); apq = red8(apq); aqq = red8(aqq);
        float c, s;
        if (jrot(app, apq, aqq, c, s)) {
#pragma unroll
          for (int j = 0; j < 4; ++j) {
            float4 np, nq;
            rot4(c, s, ce[j], co[j], np, nq);
            ce[j] = nq; co[j] = np;  // always-swap
          }
        } else {
#pragma unroll
          for (int j = 0; j < 4; ++j) { float4 t = ce[j]; ce[j] = co[j]; co[j] = t; }
        }
      }
      // B-step: slots (2o+1, 2o+2): publish ce right-ward through LDS.
      if (o > 0) {
#pragma unroll
        for (int j = 0; j < 4; ++j) M[o * 33 + l + 8 * j] = ce[j];
      }
      waitlds();
      if (o < 7) {
        float4 r4[4];
#pragma unroll
        for (int j = 0; j < 4; ++j) r4[j] = M[(o + 1) * 33 + l + 8 * j];
        float app = 0.f, apq = 0.f, aqq = 0.f;
#pragma unroll
        for (int j = 0; j < 4; ++j) {
          app += dot4(co[j], co[j]);
          apq += dot4(co[j], r4[j]);
          aqq += dot4(r4[j], r4[j]);
        }
        app = red8(app); apq = red8(apq); aqq = red8(aqq);
        float c, s;
        if (jrot(app, apq, aqq, c, s)) {
#pragma unroll
          for (int j = 0; j < 4; ++j) {
            float4 np, nq;
            rot4(c, s, co[j], r4[j], np, nq);
            M[(o + 1) * 33 + l + 8 * j] = np;  // handoff (swap)
            co[j] = nq;
          }
        } else {  // identity rotation, still swap for schedule coverage
#pragma unroll
          for (int j = 0; j < 4; ++j) {
            M[(o + 1) * 33 + l + 8 * j] = co[j];
            co[j] = r4[j];
          }
        }
      }
      waitlds();
      if (o > 0) {
#pragma unroll
        for (int j = 0; j < 4; ++j) ce[j] = M[o * 33 + l + 8 * j];
      }
    }
    // 16 always-swap odd-even steps reverse the 16 slots -> ce/co sets
    // swapped position roles; swap back (register rename, ~free).
#pragma unroll
    for (int j = 0; j < 4; ++j) { float4 t = ce[j]; ce[j] = co[j]; co[j] = t; }

    // ---- 15 tournament steps: cross-only meeting + position rotation -----
#pragma unroll 1
    for (int st = 0; st < 15; ++st) {
      // Meeting: ring the co-half through the octets; round k rotates
      // (ce[o], Q[(o+k)&7]). 8 rotations, 7 passes (last pass skipped:
      // co ends as Q[(o+7)&7] -- a permutation within the half, fine).
      float4 qv[4];
#pragma unroll
      for (int j = 0; j < 4; ++j) qv[j] = co[j];
#pragma unroll 1
      for (int k = 0; k < 8; ++k) {
        float app = 0.f, apq = 0.f, aqq = 0.f;
#pragma unroll
        for (int j = 0; j < 4; ++j) {
          app += dot4(ce[j], ce[j]);
          apq += dot4(ce[j], qv[j]);
          aqq += dot4(qv[j], qv[j]);
        }
        app = red8(app); apq = red8(apq); aqq = red8(aqq);
        float c, s;
        if (jrot(app, apq, aqq, c, s)) {
#pragma unroll
          for (int j = 0; j < 4; ++j) {
            float4 np, nq;
            rot4(c, s, ce[j], qv[j], np, nq);
            ce[j] = np; qv[j] = nq;
          }
        }
        if (k < 7) {  // pass qv: write my slot, take right neighbor's
#pragma unroll
          for (int j = 0; j < 4; ++j) M[o * 33 + l + 8 * j] = qv[j];
          waitlds();
#pragma unroll
          for (int j = 0; j < 4; ++j) qv[j] = M[((o + 1) & 7) * 33 + l + 8 * j];
        }
      }
#pragma unroll
      for (int j = 0; j < 4; ++j) co[j] = qv[j];

      // Position rotation through the outer posslot buffer (3 barriers:
      // meeting areas and posslots overlay the same 64 KB).
      __syncthreads();
#pragma unroll
      for (int j = 0; j < 4; ++j) {
        buf[dst_ce * 256 + o * 32 + l + 8 * j] = ce[j];
        buf[dst_co * 256 + o * 32 + l + 8 * j] = co[j];
      }
      __syncthreads();
#pragma unroll
      for (int j = 0; j < 4; ++j) {
        ce[j] = buf[W * 256 + o * 32 + l + 8 * j];
        co[j] = buf[(15 - W) * 256 + o * 32 + l + 8 * j];
      }
      __syncthreads();
    }
  }

  // Emit all 128 (unnormalized) eigenvector candidates + squared norms.
  // Column order is arbitrary -- select_k ranks by norm only.
  float ne = 0.f, no_ = 0.f;
#pragma unroll
  for (int j = 0; j < 4; ++j) {
    ne += dot4(ce[j], ce[j]);
    no_ += dot4(co[j], co[j]);
  }
  ne = red8(ne);
  no_ = red8(no_);
  const int ie = W * 16 + 2 * o;
  float4* Ve = (float4*)(Vfull + ((size_t)m * DD + ie) * DD);
  float4* Vo = (float4*)(Vfull + ((size_t)m * DD + ie + 1) * DD);
#pragma unroll
  for (int j = 0; j < 4; ++j) {
    Ve[l + 8 * j] = ce[j];
    Vo[l + 8 * j] = co[j];
  }
  if (l == 0) {
    normg[m * DD + ie] = ne;       // |col|^2 = lambda^2
    normg[m * DD + ie + 1] = no_;
  }
}

// ---------------- K2b: rank-select top-64 columns, normalize -> Vt ---------
__global__ __launch_bounds__(128) void select_k(const float* __restrict__ Vfull,
                                                const float* __restrict__ normg,
                                                float* __restrict__ Vt) {
  const int m = blockIdx.x;
  const int t = threadIdx.x;  // 0..127
  __shared__ float n[DD];
  __shared__ int inv[RR];
  __shared__ float scl[RR];
  n[t] = normg[m * DD + t];
  __syncthreads();
  float nt = n[t];
  int rk = 0;
  for (int k = 0; k < DD; ++k) {
    float nk = n[k];
    rk += ((nk > nt) || (nk == nt && k < t)) ? 1 : 0;
  }
  if (rk < RR) { inv[rk] = t; scl[rk] = 1.f / sqrtf(nt); }
  __syncthreads();
  for (int r = 0; r < RR; ++r) {
    Vt[((size_t)m * RR + r) * DD + t] =
        Vfull[((size_t)m * DD + inv[r]) * DD + t] * scl[r];
  }
}

// ---------------- K4: W = X @ Vt^T  (2048x64 per matrix) -------------------
__global__ __launch_bounds__(256) void gemm1_k(const float* __restrict__ X,
                                               const float* __restrict__ Vt,
                                               float* __restrict__ W) {
  const int m = blockIdx.y;
  const int s0 = blockIdx.x * 32;
  const int tid = threadIdx.x;
  __shared__ __align__(16) float VtT[128 * 68];  // [c][r], 34.8 KB
  __shared__ __align__(16) float Xs[32 * 132];   // padded, 16.9 KB
  const float* Vm = Vt + (size_t)m * RR * DD;
  for (int t = tid; t < RR * DD; t += 256) {
    int r = t >> 7, c = t & 127;
    VtT[c * 68 + r] = Vm[t];
  }
  const float* Xm = X + ((size_t)m * SEQ + s0) * DD;
  for (int t = tid; t < 1024; t += 256) {  // 32 rows x 32 float4
    int s = t >> 5, c4 = t & 31;
    *(float4*)&Xs[s * 132 + 4 * c4] = *(const float4*)&Xm[(size_t)s * DD + 4 * c4];
  }
  __syncthreads();
  const int ti = tid >> 4;  // 0..15 -> rows 2ti, 2ti+1
  const int tj = tid & 15;  // cols 4tj..+3
  float acc[2][4] = {{0.f, 0.f, 0.f, 0.f}, {0.f, 0.f, 0.f, 0.f}};
#pragma unroll 4
  for (int k = 0; k < DD; ++k) {
    float a0 = Xs[(2 * ti) * 132 + k];
    float a1 = Xs[(2 * ti + 1) * 132 + k];
    float4 bv = *(float4*)&VtT[k * 68 + 4 * tj];
    acc[0][0] += a0 * bv.x; acc[0][1] += a0 * bv.y;
    acc[0][2] += a0 * bv.z; acc[0][3] += a0 * bv.w;
    acc[1][0] += a1 * bv.x; acc[1][1] += a1 * bv.y;
    acc[1][2] += a1 * bv.z; acc[1][3] += a1 * bv.w;
  }
  float* Wm = W + ((size_t)m * SEQ + s0) * RR;
#pragma unroll
  for (int d = 0; d < 2; ++d) {
    float4 v = make_float4(acc[d][0], acc[d][1], acc[d][2], acc[d][3]);
    *(float4*)&Wm[(size_t)(2 * ti + d) * RR + 4 * tj] = v;
  }
}

// ---------------- K5: out = W @ Vt  (2048x128 per matrix) ------------------
__global__ __launch_bounds__(256) void gemm2_k(const float* __restrict__ W,
                                               const float* __restrict__ Vt,
                                               float* __restrict__ out) {
  const int m = blockIdx.y;
  const int s0 = blockIdx.x * 32;
  const int tid = threadIdx.x;
  __shared__ __align__(16) float Vts[64 * 132];  // 33.8 KB
  __shared__ __align__(16) float Ws[32 * 68];    // 8.7 KB
  const float* Vm = Vt + (size_t)m * RR * DD;
  for (int t = tid; t < 2048; t += 256) {  // 64 rows x 32 float4
    int r = t >> 5, c4 = t & 31;
    *(float4*)&Vts[r * 132 + 4 * c4] = *(const float4*)&Vm[(size_t)r * DD + 4 * c4];
  }
  const float* Wm = W + ((size_t)m * SEQ + s0) * RR;
  for (int t = tid; t < 512; t += 256) {  // 32 rows x 16 float4
    int s = t >> 4, c4 = t & 15;
    *(float4*)&Ws[s * 68 + 4 * c4] = *(const float4*)&Wm[(size_t)s * RR + 4 * c4];
  }
  __syncthreads();
  const int ti = tid >> 5;  // 0..7 -> rows 4ti..+3
  const int tj = tid & 31;  // cols 4tj..+3
  float acc[4][4] = {{0.f,0.f,0.f,0.f},{0.f,0.f,0.f,0.f},
                     {0.f,0.f,0.f,0.f},{0.f,0.f,0.f,0.f}};
#pragma unroll 4
  for (int k = 0; k < RR; ++k) {
    float4 bv = *(float4*)&Vts[k * 132 + 4 * tj];
    float a0 = Ws[(4 * ti + 0) * 68 + k];
    float a1 = Ws[(4 * ti + 1) * 68 + k];
    float a2 = Ws[(4 * ti + 2) * 68 + k];
    float a3 = Ws[(4 * ti + 3) * 68 + k];
    acc[0][0] += a0 * bv.x; acc[0][1] += a0 * bv.y;
    acc[0][2] += a0 * bv.z; acc[0][3] += a0 * bv.w;
    acc[1][0] += a1 * bv.x; acc[1][1] += a1 * bv.y;
    acc[1][2] += a1 * bv.z; acc[1][3] += a1 * bv.w;
    acc[2][0] += a2 * bv.x; acc[2][1] += a2 * bv.y;
    acc[2][2] += a2 * bv.z; acc[2][3] += a2 * bv.w;
    acc[3][0] += a3 * bv.x; acc[3][1] += a3 * bv.y;
    acc[3][2] += a3 * bv.z; acc[3][3] += a3 * bv.w;
  }
  float* Om = out + ((size_t)m * SEQ + s0) * DD;
#pragma unroll
  for (int d = 0; d < 4; ++d) {
    float4 v = make_float4(acc[d][0], acc[d][1], acc[d][2], acc[d][3]);
    *(float4*)&Om[(size_t)(4 * ti + d) * DD + 4 * tj] = v;
  }
}

extern "C" void kernel_launch(void* const* d_in, const int* in_sizes, int n_in,
                              void* d_out, int out_size, void* d_ws, size_t ws_size,
                              hipStream_t stream) {
  (void)in_sizes; (void)n_in; (void)out_size; (void)ws_size;
  const float* X = (const float*)d_in[0];  // rank (d_in[1]) is fixed at 64
  float* out = (float*)d_out;
  char* ws = (char*)d_ws;
  float* G = (float*)ws;
  float* Vfull = (float*)(ws + OFF_VFULL);
  float* normg = (float*)(ws + OFF_NORM);
  float* Vt = (float*)(ws + OFF_VT);
  float* W = (float*)ws;  // overlays dead G/Vfull/normg

  gram_k<<<dim3(4, NM), 256, 0, stream>>>(X, G);
  jacobi_hier_k<<<NM, 512, 0, stream>>>(G, Vfull, normg);
  select_k<<<NM, 128, 0, stream>>>(Vfull, normg, Vt);
  gemm1_k<<<dim3(SEQ / 32, NM), 256, 0, stream>>>(X, Vt, W);
  gemm2_k<<<dim3(SEQ / 32, NM), 256, 0, stream>>>(W, Vt, out);
}